// Round 6
// baseline (349.414 us; speedup 1.0000x reference)
//
#include <hip/hip_runtime.h>

// ---------------------------------------------------------------------------
// MHA forward, bf16 MFMA pipeline. Round 12 = round-11 (proven 343.3us) with
// ONE change: attn_fwd K/V prefetch depth 1 -> 2. Tiles t and t+1 held in
// statically-named register sets A/B; after storing tile t to LDS, tile t+2
// is issued into the freed set. Loads get 2 tiles of compute to land ->
// the vmcnt stall at the staging store (the ~2400cy/tile hole; true MFMA
// occupancy ~8%) should collapse. Main loop unrolled x2 (kv0 += 128) so all
// register indices are compile-time static (rule #20).
// GEMMs/converts/swizzles byte-identical to round 11.
// ---------------------------------------------------------------------------

typedef __bf16 bf16;
typedef bf16 bf16x4 __attribute__((ext_vector_type(4)));
typedef bf16 bf16x8 __attribute__((ext_vector_type(8)));
typedef float f32x4 __attribute__((ext_vector_type(4)));

__device__ __forceinline__ void gld_lds16(const void* g, void* l) {
  __builtin_amdgcn_global_load_lds((__attribute__((address_space(1))) void*)g,
                                   (__attribute__((address_space(3))) void*)l,
                                   16, 0, 0);
}

// ---------------------------------------------------------------------------
// Fused converts. Activations: 2,097,152 float4 each -> grid (8192, 3).
__global__ __launch_bounds__(256) void cvt3(const float* __restrict__ a,
                                            const float* __restrict__ b,
                                            const float* __restrict__ c,
                                            bf16* __restrict__ oa,
                                            bf16* __restrict__ ob,
                                            bf16* __restrict__ oc) {
  const int z = blockIdx.y;
  const float* s = (z == 0) ? a : (z == 1) ? b : c;
  bf16* d = (z == 0) ? oa : (z == 1) ? ob : oc;
  const int i = blockIdx.x * 256 + threadIdx.x;
  float4 f = reinterpret_cast<const float4*>(s)[i];
  bf16x4 o = {(bf16)f.x, (bf16)f.y, (bf16)f.z, (bf16)f.w};
  reinterpret_cast<bf16x4*>(d)[i] = o;
}

// Weights: 262,144 float4 each -> grid (1024, 4).
__global__ __launch_bounds__(256) void cvt4(const float* __restrict__ a,
                                            const float* __restrict__ b,
                                            const float* __restrict__ c,
                                            const float* __restrict__ dd,
                                            bf16* __restrict__ oa,
                                            bf16* __restrict__ ob,
                                            bf16* __restrict__ oc,
                                            bf16* __restrict__ od) {
  const int z = blockIdx.y;
  const float* s = (z == 0) ? a : (z == 1) ? b : (z == 2) ? c : dd;
  bf16* d = (z == 0) ? oa : (z == 1) ? ob : (z == 2) ? oc : od;
  const int i = blockIdx.x * 256 + threadIdx.x;
  float4 f = reinterpret_cast<const float4*>(s)[i];
  bf16x4 o = {(bf16)f.x, (bf16)f.y, (bf16)f.z, (bf16)f.w};
  reinterpret_cast<bf16x4*>(d)[i] = o;
}

// ---------------------------------------------------------------------------
// Proven GEMM core: 128x128 tile, BK=32, global_load_lds width=16,
// unswizzled LDS, 16x16x32 bf16 MFMA. C = A[M,1024] @ W[1024,1024]^T.
__device__ __forceinline__ void gemm_core(const bf16* __restrict__ A,
                                          const bf16* __restrict__ B,
                                          bf16* As, bf16* Bs, int t,
                                          int m0, int n0, f32x4 acc[4][4]) {
  constexpr int K = 1024;
  const int lane = t & 63;
  const int wave = t >> 6;
  const int wm = wave >> 1, wn = wave & 1;
  const int r16 = lane & 15, quad = lane >> 4;

  for (int k0 = 0; k0 < K; k0 += 32) {
    __syncthreads();
#pragma unroll
    for (int hh = 0; hh < 2; ++hh) {
      const int c = t + hh * 256;
      const int row = c >> 2, kk = (c & 3) * 8;
      gld_lds16(A + (size_t)(m0 + row) * K + k0 + kk, As + c * 8);
      gld_lds16(B + (size_t)(n0 + row) * K + k0 + kk, Bs + c * 8);
    }
    __syncthreads();
    bf16x8 af[4], bfr[4];
#pragma unroll
    for (int i = 0; i < 4; ++i)
      af[i] = *(const bf16x8*)&As[(wm * 64 + i * 16 + r16) * 32 + quad * 8];
#pragma unroll
    for (int i = 0; i < 4; ++i)
      bfr[i] = *(const bf16x8*)&Bs[(wn * 64 + i * 16 + r16) * 32 + quad * 8];
#pragma unroll
    for (int mi = 0; mi < 4; ++mi)
#pragma unroll
      for (int ni = 0; ni < 4; ++ni)
        acc[mi][ni] = __builtin_amdgcn_mfma_f32_16x16x32_bf16(af[mi], bfr[ni],
                                                              acc[mi][ni], 0, 0, 0);
  }
}

// Fused Q/K/V projections. Work remapped XCD-aware: the 8 n-blocks sharing
// one A-panel (same z,y) are co-XCD. Q,K -> [B,H,S,64] (Q scaled);
// V -> [B,H,64,S] transposed.
__global__ __launch_bounds__(256) void gemm_qkv(
    const bf16* __restrict__ qb, const bf16* __restrict__ kb,
    const bf16* __restrict__ vb, const bf16* __restrict__ Wqb,
    const bf16* __restrict__ Wkb, const bf16* __restrict__ Wvb,
    const float* __restrict__ bq, const float* __restrict__ bk,
    const float* __restrict__ bv, bf16* __restrict__ Qp,
    bf16* __restrict__ Kp, bf16* __restrict__ VTt, float qscale) {
  __shared__ alignas(16) bf16 As[128 * 32];
  __shared__ alignas(16) bf16 Bs[128 * 32];

  // XCD-aware bijective swizzle over all 1536 blocks (= 8 XCDs * 192).
  const int lin = blockIdx.x + (blockIdx.y << 3) + (blockIdx.z << 9);
  const int w = ((lin & 7) * 192) + (lin >> 3);
  const int which = w >> 9;          // 0..2
  const int rem = w & 511;
  const int m0 = (rem >> 3) * 128;   // y' * 128
  const int n0 = (rem & 7) * 128;    // x' * 128

  const bf16* A = (which == 0) ? qb : (which == 1) ? kb : vb;
  const bf16* W = (which == 0) ? Wqb : (which == 1) ? Wkb : Wvb;
  const float* bias = (which == 0) ? bq : (which == 1) ? bk : bv;
  const float oscale = (which == 0) ? qscale : 1.0f;
  bf16* Cb = (which == 0) ? Qp : (which == 1) ? Kp : VTt;

  const int t = threadIdx.x;
  f32x4 acc[4][4] = {};
  gemm_core(A, W, As, Bs, t, m0, n0, acc);

  const int lane = t & 63, wave = t >> 6;
  const int wm = wave >> 1, wn = wave & 1;
  const int r16 = lane & 15, quad = lane >> 4;
#pragma unroll
  for (int mi = 0; mi < 4; ++mi) {
    const int m = m0 + wm * 64 + mi * 16 + quad * 4;
#pragma unroll
    for (int ni = 0; ni < 4; ++ni) {
      const int n = n0 + wn * 64 + ni * 16 + r16;
      const float bv_ = bias[n];
      const int h = n >> 6, dh = n & 63;
      if (which < 2) {
#pragma unroll
        for (int i = 0; i < 4; ++i) {
          const int mm = m + i;
          const int b = mm >> 11, s = mm & 2047;
          Cb[(((size_t)(b * 16 + h)) * 2048 + s) * 64 + dh] =
              (bf16)((acc[mi][ni][i] + bv_) * oscale);
        }
      } else {
        const int b = m >> 11, s = m & 2047;
        bf16x4 pk;
#pragma unroll
        for (int i = 0; i < 4; ++i) pk[i] = (bf16)(acc[mi][ni][i] + bv_);
        *(bf16x4*)&Cb[(((size_t)(b * 16 + h)) * 64 + dh) * 2048 + s] = pk;
      }
    }
  }
}

// Final projection: fp32 out + bias. XCD swizzle (512 = 8*64).
__global__ __launch_bounds__(256) void gemm_out(const bf16* __restrict__ A,
                                                const bf16* __restrict__ W,
                                                const float* __restrict__ bias,
                                                float* __restrict__ Cf) {
  __shared__ alignas(16) bf16 As[128 * 32];
  __shared__ alignas(16) bf16 Bs[128 * 32];
  const int t = threadIdx.x;

  const int lin = blockIdx.x + (blockIdx.y << 3);
  const int w = ((lin & 7) << 6) + (lin >> 3);
  const int m0 = (w >> 3) * 128;
  const int n0 = (w & 7) * 128;

  f32x4 acc[4][4] = {};
  gemm_core(A, W, As, Bs, t, m0, n0, acc);

  const int lane = t & 63, wave = t >> 6;
  const int wm = wave >> 1, wn = wave & 1;
  const int r16 = lane & 15, quad = lane >> 4;
#pragma unroll
  for (int mi = 0; mi < 4; ++mi) {
    const int m = m0 + wm * 64 + mi * 16 + quad * 4;
#pragma unroll
    for (int ni = 0; ni < 4; ++ni) {
      const int n = n0 + wn * 64 + ni * 16 + r16;
      const float bv_ = bias[n];
#pragma unroll
      for (int i = 0; i < 4; ++i)
        Cf[(size_t)(m + i) * 1024 + n] = acc[mi][ni][i] + bv_;
    }
  }
}

// ---------------------------------------------------------------------------
// Flash attention, S^T formulation, no-max softmax. grid = (S/128, B*H),
// 256 threads (4 waves x 32 q). LDS rows padded to 72 el. Round-11 structure
// + 2-deep K/V register prefetch (tiles t, t+1 in named sets A/B; tile t+2
// issued after A's LDS store). Loop unrolled x2 so names are static.
__global__ __launch_bounds__(256) void attn_fwd(const bf16* __restrict__ Qp,
                                                const bf16* __restrict__ Kp,
                                                const bf16* __restrict__ VT,
                                                bf16* __restrict__ AO) {
  __shared__ alignas(16) bf16 Ks[64 * 72];   // [kv][dk], stride 72
  __shared__ alignas(16) bf16 Vs[64 * 72];   // [dk][kv], stride 72
  __shared__ alignas(16) bf16 Ps[128 * 72];  // [q][kv], stride 72
  __shared__ float Lr[128];                  // per-q row-sum scratch
  const int t = threadIdx.x, lane = t & 63, wave = t >> 6;
  const int r16 = lane & 15, quad = lane >> 4;

  // XCD-aware bijective swizzle (1024 = 8*128): XCD x owns 8 contiguous bh.
  const int lin = blockIdx.x + (blockIdx.y << 4);   // 0..1023
  const int w = ((lin & 7) << 7) + (lin >> 3);
  const int bh = w >> 4;
  const int q0 = (w & 15) << 7;

  const int qw = wave * 32;  // wave's local q base
  const bf16* Qb = Qp + (size_t)bh * (2048 * 64);
  const bf16* Kb = Kp + (size_t)bh * (2048 * 64);
  const bf16* Vb = VT + (size_t)bh * (64 * 2048);

  // Q fragments from global, used as B-operand (n=q=lane&15, k=dk=quad*8+j).
  bf16x8 qf[2][2];
#pragma unroll
  for (int nq = 0; nq < 2; ++nq)
#pragma unroll
    for (int ks = 0; ks < 2; ++ks)
      qf[nq][ks] = *(const bf16x8*)&Qb[(size_t)(q0 + qw + nq * 16 + r16) * 64 +
                                       ks * 32 + quad * 8];

  // staging chunks: c = 2t, 2t+1 over 512 chunks
  const int c0 = t * 2, c1 = t * 2 + 1;
  const int kr0 = c0 >> 3, kc0 = (c0 & 7) * 8;
  const int kr1 = c1 >> 3, kc1 = (c1 & 7) * 8;

  // 2-deep prefetch: set A = tile kv0, set B = tile kv0+64.
  bf16x8 kA0 = *(const bf16x8*)(Kb + (size_t)kr0 * 64 + kc0);
  bf16x8 kA1 = *(const bf16x8*)(Kb + (size_t)kr1 * 64 + kc1);
  bf16x8 vA0 = *(const bf16x8*)(Vb + (size_t)kr0 * 2048 + kc0);
  bf16x8 vA1 = *(const bf16x8*)(Vb + (size_t)kr1 * 2048 + kc1);
  bf16x8 kB0 = *(const bf16x8*)(Kb + (size_t)(64 + kr0) * 64 + kc0);
  bf16x8 kB1 = *(const bf16x8*)(Kb + (size_t)(64 + kr1) * 64 + kc1);
  bf16x8 vB0 = *(const bf16x8*)(Vb + (size_t)kr0 * 2048 + 64 + kc0);
  bf16x8 vB1 = *(const bf16x8*)(Vb + (size_t)kr1 * 2048 + 64 + kc1);

  f32x4 o[2][4] = {};
  float lrow[2] = {0.f, 0.f};  // per-lane partial sum for q = qw + nq*16 + r16

  // per-tile compute from LDS (kf reads, QK^T, exp, P store, PV)
  auto compute = [&]() {
    bf16x8 kf[4][2];
#pragma unroll
    for (int mi = 0; mi < 4; ++mi) {
      kf[mi][0] = *(const bf16x8*)&Ks[(mi * 16 + r16) * 72 + quad * 8];
      kf[mi][1] = *(const bf16x8*)&Ks[(mi * 16 + r16) * 72 + 32 + quad * 8];
    }
#pragma unroll
    for (int nq = 0; nq < 2; ++nq) {
      const int qL = qw + nq * 16 + r16;
#pragma unroll
      for (int mi = 0; mi < 4; ++mi) {
        f32x4 z = {};
        z = __builtin_amdgcn_mfma_f32_16x16x32_bf16(kf[mi][0], qf[nq][0], z, 0, 0, 0);
        z = __builtin_amdgcn_mfma_f32_16x16x32_bf16(kf[mi][1], qf[nq][1], z, 0, 0, 0);
        bf16x4 pk;
#pragma unroll
        for (int i = 0; i < 4; ++i) {
          const float p = __builtin_amdgcn_exp2f(z[i]);
          lrow[nq] += p;
          pk[i] = (bf16)p;
        }
        *(bf16x4*)&Ps[qL * 72 + mi * 16 + quad * 4] = pk;
      }
    }
#pragma unroll
    for (int ks = 0; ks < 2; ++ks) {
      bf16x8 pf[2];
#pragma unroll
      for (int mi = 0; mi < 2; ++mi)
        pf[mi] = *(const bf16x8*)&Ps[(qw + mi * 16 + r16) * 72 + ks * 32 + quad * 8];
#pragma unroll
      for (int ni = 0; ni < 4; ++ni) {
        bf16x8 vf = *(const bf16x8*)&Vs[(ni * 16 + r16) * 72 + ks * 32 + quad * 8];
#pragma unroll
        for (int mi = 0; mi < 2; ++mi)
          o[mi][ni] = __builtin_amdgcn_mfma_f32_16x16x32_bf16(pf[mi], vf, o[mi][ni], 0, 0, 0);
      }
    }
  };

  for (int kv0 = 0; kv0 < 2048; kv0 += 128) {
    // ---- phase A: tile kv0 (held in set A) ----
    __syncthreads();
    *(bf16x8*)&Ks[kr0 * 72 + kc0] = kA0;
    *(bf16x8*)&Ks[kr1 * 72 + kc1] = kA1;
    *(bf16x8*)&Vs[kr0 * 72 + kc0] = vA0;
    *(bf16x8*)&Vs[kr1 * 72 + kc1] = vA1;
    __syncthreads();
    if (kv0 + 128 < 2048) {  // issue tile kv0+128 into freed set A
      const int nx = kv0 + 128;
      kA0 = *(const bf16x8*)(Kb + (size_t)(nx + kr0) * 64 + kc0);
      kA1 = *(const bf16x8*)(Kb + (size_t)(nx + kr1) * 64 + kc1);
      vA0 = *(const bf16x8*)(Vb + (size_t)kr0 * 2048 + nx + kc0);
      vA1 = *(const bf16x8*)(Vb + (size_t)kr1 * 2048 + nx + kc1);
    }
    compute();

    // ---- phase B: tile kv0+64 (held in set B) ----
    __syncthreads();
    *(bf16x8*)&Ks[kr0 * 72 + kc0] = kB0;
    *(bf16x8*)&Ks[kr1 * 72 + kc1] = kB1;
    *(bf16x8*)&Vs[kr0 * 72 + kc0] = vB0;
    *(bf16x8*)&Vs[kr1 * 72 + kc1] = vB1;
    __syncthreads();
    if (kv0 + 192 < 2048) {  // issue tile kv0+192 into freed set B
      const int nx = kv0 + 192;
      kB0 = *(const bf16x8*)(Kb + (size_t)(nx + kr0) * 64 + kc0);
      kB1 = *(const bf16x8*)(Kb + (size_t)(nx + kr1) * 64 + kc1);
      vB0 = *(const bf16x8*)(Vb + (size_t)kr0 * 2048 + nx + kc0);
      vB1 = *(const bf16x8*)(Vb + (size_t)kr1 * 2048 + nx + kc1);
    }
    compute();
  }

  // move l from softmax-lanes (q = qw+nq*16+r16) to epilogue-lanes via LDS
#pragma unroll
  for (int nq = 0; nq < 2; ++nq) {
    float s = lrow[nq];
    s += __shfl_xor(s, 16);
    s += __shfl_xor(s, 32);  // sum across quads -> full row sum
    if (quad == 0) Lr[qw + nq * 16 + r16] = s;
  }
  f32x4 lr[2];
#pragma unroll
  for (int mi = 0; mi < 2; ++mi)
    lr[mi] = *(const f32x4*)&Lr[qw + mi * 16 + quad * 4];  // same-wave RAW

  const int b = bh >> 4, h = bh & 15;
#pragma unroll
  for (int mi = 0; mi < 2; ++mi)
#pragma unroll
    for (int i = 0; i < 4; ++i) {
      const float rl = 1.0f / lr[mi][i];
      const int sq = q0 + qw + mi * 16 + quad * 4 + i;
      const size_t base = ((size_t)(b * 2048 + sq)) * 1024 + h * 64;
#pragma unroll
      for (int ni = 0; ni < 4; ++ni)
        AO[base + ni * 16 + r16] = (bf16)(o[mi][ni][i] * rl);
    }
}

// ---------------------------------------------------------------------------
extern "C" void kernel_launch(void* const* d_in, const int* in_sizes, int n_in,
                              void* d_out, int out_size, void* d_ws, size_t ws_size,
                              hipStream_t stream) {
  const float* q  = (const float*)d_in[0];
  const float* k  = (const float*)d_in[1];
  const float* v  = (const float*)d_in[2];
  const float* Wq = (const float*)d_in[3];
  const float* bq = (const float*)d_in[4];
  const float* Wk = (const float*)d_in[5];
  const float* bk = (const float*)d_in[6];
  const float* Wv = (const float*)d_in[7];
  const float* bv = (const float*)d_in[8];
  const float* Wo = (const float*)d_in[9];
  const float* bo = (const float*)d_in[10];

  char* ws = (char*)d_ws;
  const size_t MB = 1ull << 20;
  bf16* qb  = (bf16*)(ws + 0);         // 16 MB (reused as AO after Q-proj)
  bf16* kb  = (bf16*)(ws + 16 * MB);
  bf16* vb  = (bf16*)(ws + 32 * MB);
  bf16* Wqb = (bf16*)(ws + 48 * MB);
  bf16* Wkb = (bf16*)(ws + 50 * MB);
  bf16* Wvb = (bf16*)(ws + 52 * MB);
  bf16* Wob = (bf16*)(ws + 54 * MB);
  bf16* Qp  = (bf16*)(ws + 56 * MB);   // [B,H,S,64]
  bf16* Kp  = (bf16*)(ws + 72 * MB);   // [B,H,S,64]
  bf16* VTt = (bf16*)(ws + 88 * MB);   // [B,H,64,S]
  bf16* AO  = qb;

  cvt3<<<dim3(8192, 3), 256, 0, stream>>>(q, k, v, qb, kb, vb);
  cvt4<<<dim3(1024, 4), 256, 0, stream>>>(Wq, Wk, Wv, Wo, Wqb, Wkb, Wvb, Wob);

  const float qscale = 0.125f * 1.44269504088896340736f;  // 1/sqrt(64) * log2(e)
  gemm_qkv<<<dim3(8, 64, 3), 256, 0, stream>>>(qb, kb, vb, Wqb, Wkb, Wvb,
                                               bq, bk, bv, Qp, Kp, VTt, qscale);

  attn_fwd<<<dim3(16, 64), 256, 0, stream>>>(Qp, Kp, VTt, AO);

  gemm_out<<<dim3(8, 64), 256, 0, stream>>>(AO, Wob, bo, (float*)d_out);
}

// Round 7
// 342.599 us; speedup vs baseline: 1.0199x; 1.0199x over previous
//
#include <hip/hip_runtime.h>

// ---------------------------------------------------------------------------
// MHA forward, bf16 MFMA pipeline. Round 13 = recombination of proven parts:
//  - attn_fwd: round-6 version VERBATIM (102.7us measured; no XCD swizzle,
//    no setprio, depth-1 reg prefetch, Ps via LDS). Attn swizzle measured
//    harmful (+6us, R11); deeper prefetch harmful (+4.5us, R12).
//  - gemm_qkv / gemm_out: XCD-aware bijective swizzles (R11, worth -13us:
//    co-locates the 8 n-blocks sharing an A-panel on one XCD's L2).
//  - converts: unchanged.
// ---------------------------------------------------------------------------

typedef __bf16 bf16;
typedef bf16 bf16x4 __attribute__((ext_vector_type(4)));
typedef bf16 bf16x8 __attribute__((ext_vector_type(8)));
typedef float f32x4 __attribute__((ext_vector_type(4)));

__device__ __forceinline__ void gld_lds16(const void* g, void* l) {
  __builtin_amdgcn_global_load_lds((__attribute__((address_space(1))) void*)g,
                                   (__attribute__((address_space(3))) void*)l,
                                   16, 0, 0);
}

// ---------------------------------------------------------------------------
// Fused converts. Activations: 2,097,152 float4 each -> grid (8192, 3).
__global__ __launch_bounds__(256) void cvt3(const float* __restrict__ a,
                                            const float* __restrict__ b,
                                            const float* __restrict__ c,
                                            bf16* __restrict__ oa,
                                            bf16* __restrict__ ob,
                                            bf16* __restrict__ oc) {
  const int z = blockIdx.y;
  const float* s = (z == 0) ? a : (z == 1) ? b : c;
  bf16* d = (z == 0) ? oa : (z == 1) ? ob : oc;
  const int i = blockIdx.x * 256 + threadIdx.x;
  float4 f = reinterpret_cast<const float4*>(s)[i];
  bf16x4 o = {(bf16)f.x, (bf16)f.y, (bf16)f.z, (bf16)f.w};
  reinterpret_cast<bf16x4*>(d)[i] = o;
}

// Weights: 262,144 float4 each -> grid (1024, 4).
__global__ __launch_bounds__(256) void cvt4(const float* __restrict__ a,
                                            const float* __restrict__ b,
                                            const float* __restrict__ c,
                                            const float* __restrict__ dd,
                                            bf16* __restrict__ oa,
                                            bf16* __restrict__ ob,
                                            bf16* __restrict__ oc,
                                            bf16* __restrict__ od) {
  const int z = blockIdx.y;
  const float* s = (z == 0) ? a : (z == 1) ? b : (z == 2) ? c : dd;
  bf16* d = (z == 0) ? oa : (z == 1) ? ob : (z == 2) ? oc : od;
  const int i = blockIdx.x * 256 + threadIdx.x;
  float4 f = reinterpret_cast<const float4*>(s)[i];
  bf16x4 o = {(bf16)f.x, (bf16)f.y, (bf16)f.z, (bf16)f.w};
  reinterpret_cast<bf16x4*>(d)[i] = o;
}

// ---------------------------------------------------------------------------
// Proven GEMM core: 128x128 tile, BK=32, global_load_lds width=16,
// unswizzled LDS, 16x16x32 bf16 MFMA. C = A[M,1024] @ W[1024,1024]^T.
__device__ __forceinline__ void gemm_core(const bf16* __restrict__ A,
                                          const bf16* __restrict__ B,
                                          bf16* As, bf16* Bs, int t,
                                          int m0, int n0, f32x4 acc[4][4]) {
  constexpr int K = 1024;
  const int lane = t & 63;
  const int wave = t >> 6;
  const int wm = wave >> 1, wn = wave & 1;
  const int r16 = lane & 15, quad = lane >> 4;

  for (int k0 = 0; k0 < K; k0 += 32) {
    __syncthreads();
#pragma unroll
    for (int hh = 0; hh < 2; ++hh) {
      const int c = t + hh * 256;
      const int row = c >> 2, kk = (c & 3) * 8;
      gld_lds16(A + (size_t)(m0 + row) * K + k0 + kk, As + c * 8);
      gld_lds16(B + (size_t)(n0 + row) * K + k0 + kk, Bs + c * 8);
    }
    __syncthreads();
    bf16x8 af[4], bfr[4];
#pragma unroll
    for (int i = 0; i < 4; ++i)
      af[i] = *(const bf16x8*)&As[(wm * 64 + i * 16 + r16) * 32 + quad * 8];
#pragma unroll
    for (int i = 0; i < 4; ++i)
      bfr[i] = *(const bf16x8*)&Bs[(wn * 64 + i * 16 + r16) * 32 + quad * 8];
#pragma unroll
    for (int mi = 0; mi < 4; ++mi)
#pragma unroll
      for (int ni = 0; ni < 4; ++ni)
        acc[mi][ni] = __builtin_amdgcn_mfma_f32_16x16x32_bf16(af[mi], bfr[ni],
                                                              acc[mi][ni], 0, 0, 0);
  }
}

// Fused Q/K/V projections. Work remapped XCD-aware: the 8 n-blocks sharing
// one A-panel (same z,y) are co-XCD. Q,K -> [B,H,S,64] (Q scaled);
// V -> [B,H,64,S] transposed.
__global__ __launch_bounds__(256) void gemm_qkv(
    const bf16* __restrict__ qb, const bf16* __restrict__ kb,
    const bf16* __restrict__ vb, const bf16* __restrict__ Wqb,
    const bf16* __restrict__ Wkb, const bf16* __restrict__ Wvb,
    const float* __restrict__ bq, const float* __restrict__ bk,
    const float* __restrict__ bv, bf16* __restrict__ Qp,
    bf16* __restrict__ Kp, bf16* __restrict__ VTt, float qscale) {
  __shared__ alignas(16) bf16 As[128 * 32];
  __shared__ alignas(16) bf16 Bs[128 * 32];

  // XCD-aware bijective swizzle over all 1536 blocks (= 8 XCDs * 192).
  const int lin = blockIdx.x + (blockIdx.y << 3) + (blockIdx.z << 9);
  const int w = ((lin & 7) * 192) + (lin >> 3);
  const int which = w >> 9;          // 0..2
  const int rem = w & 511;
  const int m0 = (rem >> 3) * 128;   // y' * 128
  const int n0 = (rem & 7) * 128;    // x' * 128

  const bf16* A = (which == 0) ? qb : (which == 1) ? kb : vb;
  const bf16* W = (which == 0) ? Wqb : (which == 1) ? Wkb : Wvb;
  const float* bias = (which == 0) ? bq : (which == 1) ? bk : bv;
  const float oscale = (which == 0) ? qscale : 1.0f;
  bf16* Cb = (which == 0) ? Qp : (which == 1) ? Kp : VTt;

  const int t = threadIdx.x;
  f32x4 acc[4][4] = {};
  gemm_core(A, W, As, Bs, t, m0, n0, acc);

  const int lane = t & 63, wave = t >> 6;
  const int wm = wave >> 1, wn = wave & 1;
  const int r16 = lane & 15, quad = lane >> 4;
#pragma unroll
  for (int mi = 0; mi < 4; ++mi) {
    const int m = m0 + wm * 64 + mi * 16 + quad * 4;
#pragma unroll
    for (int ni = 0; ni < 4; ++ni) {
      const int n = n0 + wn * 64 + ni * 16 + r16;
      const float bv_ = bias[n];
      const int h = n >> 6, dh = n & 63;
      if (which < 2) {
#pragma unroll
        for (int i = 0; i < 4; ++i) {
          const int mm = m + i;
          const int b = mm >> 11, s = mm & 2047;
          Cb[(((size_t)(b * 16 + h)) * 2048 + s) * 64 + dh] =
              (bf16)((acc[mi][ni][i] + bv_) * oscale);
        }
      } else {
        const int b = m >> 11, s = m & 2047;
        bf16x4 pk;
#pragma unroll
        for (int i = 0; i < 4; ++i) pk[i] = (bf16)(acc[mi][ni][i] + bv_);
        *(bf16x4*)&Cb[(((size_t)(b * 16 + h)) * 64 + dh) * 2048 + s] = pk;
      }
    }
  }
}

// Final projection: fp32 out + bias. XCD swizzle (512 = 8*64).
__global__ __launch_bounds__(256) void gemm_out(const bf16* __restrict__ A,
                                                const bf16* __restrict__ W,
                                                const float* __restrict__ bias,
                                                float* __restrict__ Cf) {
  __shared__ alignas(16) bf16 As[128 * 32];
  __shared__ alignas(16) bf16 Bs[128 * 32];
  const int t = threadIdx.x;

  const int lin = blockIdx.x + (blockIdx.y << 3);
  const int w = ((lin & 7) << 6) + (lin >> 3);
  const int m0 = (w >> 3) * 128;
  const int n0 = (w & 7) * 128;

  f32x4 acc[4][4] = {};
  gemm_core(A, W, As, Bs, t, m0, n0, acc);

  const int lane = t & 63, wave = t >> 6;
  const int wm = wave >> 1, wn = wave & 1;
  const int r16 = lane & 15, quad = lane >> 4;
#pragma unroll
  for (int mi = 0; mi < 4; ++mi) {
    const int m = m0 + wm * 64 + mi * 16 + quad * 4;
#pragma unroll
    for (int ni = 0; ni < 4; ++ni) {
      const int n = n0 + wn * 64 + ni * 16 + r16;
      const float bv_ = bias[n];
#pragma unroll
      for (int i = 0; i < 4; ++i)
        Cf[(size_t)(m + i) * 1024 + n] = acc[mi][ni][i] + bv_;
    }
  }
}

// ---------------------------------------------------------------------------
// Flash attention, S^T formulation, no-max softmax. grid = (S/128, B*H),
// 256 threads (4 waves x 32 q). LDS rows padded to 72 el. ROUND-6 VERBATIM
// (102.7us measured): no block swizzle, depth-1 prefetch, Ps via LDS.
// S^T = K*Q^T: A=K (m=kv), B=Q^T (n=q) -> C col=lane&15=q, row=quad*4+reg=kv
// => each lane holds 4 consecutive kv for a fixed q => packed b64 P-stores.
__global__ __launch_bounds__(256) void attn_fwd(const bf16* __restrict__ Qp,
                                                const bf16* __restrict__ Kp,
                                                const bf16* __restrict__ VT,
                                                bf16* __restrict__ AO) {
  __shared__ alignas(16) bf16 Ks[64 * 72];   // [kv][dk], stride 72
  __shared__ alignas(16) bf16 Vs[64 * 72];   // [dk][kv], stride 72
  __shared__ alignas(16) bf16 Ps[128 * 72];  // [q][kv], stride 72
  __shared__ float Lr[128];                  // per-q row-sum scratch
  const int t = threadIdx.x, lane = t & 63, wave = t >> 6;
  const int r16 = lane & 15, quad = lane >> 4;
  const int bh = blockIdx.y;
  const int q0 = blockIdx.x * 128;
  const int qw = wave * 32;  // wave's local q base
  const bf16* Qb = Qp + (size_t)bh * (2048 * 64);
  const bf16* Kb = Kp + (size_t)bh * (2048 * 64);
  const bf16* Vb = VT + (size_t)bh * (64 * 2048);

  // Q fragments from global, used as B-operand (n=q=lane&15, k=dk=quad*8+j).
  bf16x8 qf[2][2];
#pragma unroll
  for (int nq = 0; nq < 2; ++nq)
#pragma unroll
    for (int ks = 0; ks < 2; ++ks)
      qf[nq][ks] = *(const bf16x8*)&Qb[(size_t)(q0 + qw + nq * 16 + r16) * 64 +
                                       ks * 32 + quad * 8];

  // staging chunks: c = 2t, 2t+1 over 512 chunks
  const int c0 = t * 2, c1 = t * 2 + 1;
  const int kr0 = c0 >> 3, kc0 = (c0 & 7) * 8;
  const int kr1 = c1 >> 3, kc1 = (c1 & 7) * 8;

  bf16x8 kreg0 = *(const bf16x8*)(Kb + (size_t)kr0 * 64 + kc0);
  bf16x8 kreg1 = *(const bf16x8*)(Kb + (size_t)kr1 * 64 + kc1);
  bf16x8 vreg0 = *(const bf16x8*)(Vb + (size_t)kr0 * 2048 + kc0);
  bf16x8 vreg1 = *(const bf16x8*)(Vb + (size_t)kr1 * 2048 + kc1);

  f32x4 o[2][4] = {};
  float lrow[2] = {0.f, 0.f};  // per-lane partial sum for q = qw + nq*16 + r16

  for (int kv0 = 0; kv0 < 2048; kv0 += 64) {
    __syncthreads();
    *(bf16x8*)&Ks[kr0 * 72 + kc0] = kreg0;
    *(bf16x8*)&Ks[kr1 * 72 + kc1] = kreg1;
    *(bf16x8*)&Vs[kr0 * 72 + kc0] = vreg0;
    *(bf16x8*)&Vs[kr1 * 72 + kc1] = vreg1;
    __syncthreads();

    if (kv0 + 64 < 2048) {
      const int nx = kv0 + 64;
      kreg0 = *(const bf16x8*)(Kb + (size_t)(nx + kr0) * 64 + kc0);
      kreg1 = *(const bf16x8*)(Kb + (size_t)(nx + kr1) * 64 + kc1);
      vreg0 = *(const bf16x8*)(Vb + (size_t)kr0 * 2048 + nx + kc0);
      vreg1 = *(const bf16x8*)(Vb + (size_t)kr1 * 2048 + nx + kc1);
    }

    // K fragments (A-operand: m=kv=lane&15 per 16-row subtile, k=dk).
    bf16x8 kf[4][2];
#pragma unroll
    for (int mi = 0; mi < 4; ++mi) {
      kf[mi][0] = *(const bf16x8*)&Ks[(mi * 16 + r16) * 72 + quad * 8];
      kf[mi][1] = *(const bf16x8*)&Ks[(mi * 16 + r16) * 72 + 32 + quad * 8];
    }

    // S^T = K*Q^T; z[i] = S^T[kv=mi*16+quad*4+i][q=qw+nq*16+r16]
#pragma unroll
    for (int nq = 0; nq < 2; ++nq) {
      const int qL = qw + nq * 16 + r16;
#pragma unroll
      for (int mi = 0; mi < 4; ++mi) {
        f32x4 z = {};
        z = __builtin_amdgcn_mfma_f32_16x16x32_bf16(kf[mi][0], qf[nq][0], z, 0, 0, 0);
        z = __builtin_amdgcn_mfma_f32_16x16x32_bf16(kf[mi][1], qf[nq][1], z, 0, 0, 0);
        // p = exp2(s); packed b64 store of 4 consecutive kv
        bf16x4 pk;
#pragma unroll
        for (int i = 0; i < 4; ++i) {
          const float p = __builtin_amdgcn_exp2f(z[i]);
          lrow[nq] += p;
          pk[i] = (bf16)p;
        }
        *(bf16x4*)&Ps[qL * 72 + mi * 16 + quad * 4] = pk;
      }
    }

    // O += P V  (pf rows qw+mi*16+r16, vf from Vs)
#pragma unroll
    for (int ks = 0; ks < 2; ++ks) {
      bf16x8 pf[2];
#pragma unroll
      for (int mi = 0; mi < 2; ++mi)
        pf[mi] = *(const bf16x8*)&Ps[(qw + mi * 16 + r16) * 72 + ks * 32 + quad * 8];
#pragma unroll
      for (int ni = 0; ni < 4; ++ni) {
        bf16x8 vf = *(const bf16x8*)&Vs[(ni * 16 + r16) * 72 + ks * 32 + quad * 8];
#pragma unroll
        for (int mi = 0; mi < 2; ++mi)
          o[mi][ni] = __builtin_amdgcn_mfma_f32_16x16x32_bf16(pf[mi], vf, o[mi][ni], 0, 0, 0);
      }
    }
  }

  // move l from softmax-lanes (q = qw+nq*16+r16) to epilogue-lanes via LDS
#pragma unroll
  for (int nq = 0; nq < 2; ++nq) {
    float s = lrow[nq];
    s += __shfl_xor(s, 16);
    s += __shfl_xor(s, 32);  // sum across quads -> full row sum
    if (quad == 0) Lr[qw + nq * 16 + r16] = s;
  }
  f32x4 lr[2];
#pragma unroll
  for (int mi = 0; mi < 2; ++mi)
    lr[mi] = *(const f32x4*)&Lr[qw + mi * 16 + quad * 4];  // same-wave RAW

  const int b = bh >> 4, h = bh & 15;
#pragma unroll
  for (int mi = 0; mi < 2; ++mi)
#pragma unroll
    for (int i = 0; i < 4; ++i) {
      const float rl = 1.0f / lr[mi][i];
      const int sq = q0 + qw + mi * 16 + quad * 4 + i;
      const size_t base = ((size_t)(b * 2048 + sq)) * 1024 + h * 64;
#pragma unroll
      for (int ni = 0; ni < 4; ++ni)
        AO[base + ni * 16 + r16] = (bf16)(o[mi][ni][i] * rl);
    }
}

// ---------------------------------------------------------------------------
extern "C" void kernel_launch(void* const* d_in, const int* in_sizes, int n_in,
                              void* d_out, int out_size, void* d_ws, size_t ws_size,
                              hipStream_t stream) {
  const float* q  = (const float*)d_in[0];
  const float* k  = (const float*)d_in[1];
  const float* v  = (const float*)d_in[2];
  const float* Wq = (const float*)d_in[3];
  const float* bq = (const float*)d_in[4];
  const float* Wk = (const float*)d_in[5];
  const float* bk = (const float*)d_in[6];
  const float* Wv = (const float*)d_in[7];
  const float* bv = (const float*)d_in[8];
  const float* Wo = (const float*)d_in[9];
  const float* bo = (const float*)d_in[10];

  char* ws = (char*)d_ws;
  const size_t MB = 1ull << 20;
  bf16* qb  = (bf16*)(ws + 0);         // 16 MB (reused as AO after Q-proj)
  bf16* kb  = (bf16*)(ws + 16 * MB);
  bf16* vb  = (bf16*)(ws + 32 * MB);
  bf16* Wqb = (bf16*)(ws + 48 * MB);
  bf16* Wkb = (bf16*)(ws + 50 * MB);
  bf16* Wvb = (bf16*)(ws + 52 * MB);
  bf16* Wob = (bf16*)(ws + 54 * MB);
  bf16* Qp  = (bf16*)(ws + 56 * MB);   // [B,H,S,64]
  bf16* Kp  = (bf16*)(ws + 72 * MB);   // [B,H,S,64]
  bf16* VTt = (bf16*)(ws + 88 * MB);   // [B,H,64,S]
  bf16* AO  = qb;

  cvt3<<<dim3(8192, 3), 256, 0, stream>>>(q, k, v, qb, kb, vb);
  cvt4<<<dim3(1024, 4), 256, 0, stream>>>(Wq, Wk, Wv, Wo, Wqb, Wkb, Wvb, Wob);

  const float qscale = 0.125f * 1.44269504088896340736f;  // 1/sqrt(64) * log2(e)
  gemm_qkv<<<dim3(8, 64, 3), 256, 0, stream>>>(qb, kb, vb, Wqb, Wkb, Wvb,
                                               bq, bk, bv, Qp, Kp, VTt, qscale);

  attn_fwd<<<dim3(16, 64), 256, 0, stream>>>(Qp, Kp, VTt, AO);

  gemm_out<<<dim3(8, 64), 256, 0, stream>>>(AO, Wob, bo, (float*)d_out);
}